// Round 1
// baseline (434.766 us; speedup 1.0000x reference)
//
#include <hip/hip_runtime.h>

#define GRIDN 64
#define NVOX (GRIDN * GRIDN * GRIDN)
#define VOXF (1.0f / 64.0f)
#define CH 256      // gaussians staged per chunk
#define BLOCK 256
#define VPT 2       // voxels per thread (consecutive x)

// LDS layout per gaussian (12 floats, 48B, float4-aligned):
// [0]=Sxx [1]=Syy [2]=Szz [3]=2*Sxy [4]=2*Sxz [5]=2*Syz
// [6]=mux [7]=muy [8]=muz [9]=dens [10]=0.25/Sxx [11]=pad

__global__ __launch_bounds__(BLOCK) void vox_kernel(
    const float* __restrict__ means, const float* __restrict__ dens,
    const float* __restrict__ scales, const float* __restrict__ rots,
    float* __restrict__ out, int N)
{
    __shared__ float lds[CH * 12];
    const int tid = threadIdx.x;
    const int v0 = (blockIdx.x * BLOCK + tid) * VPT;
    const int x = v0 & 63, y = (v0 >> 6) & 63, z = v0 >> 12;
    const float px = (x + 0.5f) * VOXF;
    const float py = (y + 0.5f) * VOXF;
    const float pz = (z + 0.5f) * VOXF;
    float acc0 = 0.f, acc1 = 0.f;

    for (int c0 = 0; c0 < N; c0 += CH) {
        // ---- stage CH gaussians: compute Sinv from quat/scales on the fly ----
        {
            const int g = c0 + tid;  // BLOCK == CH
            float qw = rots[g * 4 + 0], qx = rots[g * 4 + 1];
            float qy = rots[g * 4 + 2], qz = rots[g * 4 + 3];
            float inm = rsqrtf(qw * qw + qx * qx + qy * qy + qz * qz);
            qw *= inm; qx *= inm; qy *= inm; qz *= inm;
            float r00 = 1.f - 2.f * (qy * qy + qz * qz);
            float r01 = 2.f * (qx * qy - qw * qz);
            float r02 = 2.f * (qx * qz + qw * qy);
            float r10 = 2.f * (qx * qy + qw * qz);
            float r11 = 1.f - 2.f * (qx * qx + qz * qz);
            float r12 = 2.f * (qy * qz - qw * qx);
            float r20 = 2.f * (qx * qz - qw * qy);
            float r21 = 2.f * (qy * qz + qw * qx);
            float r22 = 1.f - 2.f * (qx * qx + qy * qy);
            float s0 = scales[g * 3 + 0], s1 = scales[g * 3 + 1], s2 = scales[g * 3 + 2];
            float i0 = 1.f / (s0 * s0), i1 = 1.f / (s1 * s1), i2 = 1.f / (s2 * s2);
            float A = r00 * r00 * i0 + r01 * r01 * i1 + r02 * r02 * i2;
            float B = r10 * r10 * i0 + r11 * r11 * i1 + r12 * r12 * i2;
            float C = r20 * r20 * i0 + r21 * r21 * i1 + r22 * r22 * i2;
            float D = r00 * r10 * i0 + r01 * r11 * i1 + r02 * r12 * i2;
            float E = r00 * r20 * i0 + r01 * r21 * i1 + r02 * r22 * i2;
            float F = r10 * r20 * i0 + r11 * r21 * i1 + r12 * r22 * i2;
            float* p = &lds[tid * 12];
            p[0] = A; p[1] = B; p[2] = C;
            p[3] = 2.f * D; p[4] = 2.f * E; p[5] = 2.f * F;
            p[6] = means[g * 3 + 0]; p[7] = means[g * 3 + 1]; p[8] = means[g * 3 + 2];
            p[9] = dens[g]; p[10] = 0.25f / A; p[11] = 0.f;
        }
        __syncthreads();

        // ---- accumulate over staged gaussians ----
        for (int j = 0; j < CH; ++j) {
            const float4* q4 = (const float4*)&lds[j * 12];
            float4 w0 = q4[0], w1 = q4[1], w2 = q4[2];
            float A = w0.x, B = w0.y, C = w0.z, D2 = w0.w;
            float E2 = w1.x, F2 = w1.y, mx = w1.z, my = w1.w;
            float mz = w2.x, de = w2.y, i4a = w2.z;

            float dy = py - my, dz = pz - mz;
            float qyz = B * dy * dy + C * dz * dz + F2 * dy * dz;
            float gx = D2 * dy + E2 * dz;
            // exact min over continuous dx of  A*dx^2 + gx*dx + qyz
            float qmin = qyz - gx * gx * i4a;
            if (__all(qmin > 30.0f)) continue;  // skipped mass <= 4096*e^-15 ~ 1e-3

            float dx0 = px - mx;
            float dx1 = dx0 + VOXF;
            float q0 = qyz + dx0 * (A * dx0 + gx);
            float q1 = qyz + dx1 * (A * dx1 + gx);
            acc0 += de * __builtin_amdgcn_exp2f(q0 * -0.72134752044f);
            acc1 += de * __builtin_amdgcn_exp2f(q1 * -0.72134752044f);
        }
        __syncthreads();
    }

    float2 r; r.x = acc0; r.y = acc1;
    *(float2*)&out[v0] = r;
}

__global__ void radii_kernel(const float* __restrict__ scales,
                             float* __restrict__ out, int N)
{
    int i = blockIdx.x * 256 + threadIdx.x;
    if (i < N) {
        float s0 = scales[i * 3 + 0], s1 = scales[i * 3 + 1], s2 = scales[i * 3 + 2];
        float m = fmaxf(s0, fmaxf(s1, s2));
        // radii = ceil(3*max_scale/VOX); written as float (harness reads flat f32)
        out[NVOX + i] = ceilf(m * 3.0f * 64.0f);
    }
}

extern "C" void kernel_launch(void* const* d_in, const int* in_sizes, int n_in,
                              void* d_out, int out_size, void* d_ws, size_t ws_size,
                              hipStream_t stream)
{
    const float* means  = (const float*)d_in[0];
    const float* dens   = (const float*)d_in[1];
    const float* scales = (const float*)d_in[2];
    const float* rots   = (const float*)d_in[3];
    float* out = (float*)d_out;
    const int N = in_sizes[1];  // densities count = 4096

    vox_kernel<<<NVOX / (BLOCK * VPT), BLOCK, 0, stream>>>(means, dens, scales, rots, out, N);
    radii_kernel<<<(N + 255) / 256, 256, 0, stream>>>(scales, out, N);
}

// Round 2
// 121.995 us; speedup vs baseline: 3.5638x; 3.5638x over previous
//
#include <hip/hip_runtime.h>

#define GRIDN 64
#define NVOX (GRIDN * GRIDN * GRIDN)
#define VOXF (1.0f / 64.0f)
#define TILE 8            // 8x8x8 voxel tile per block
#define BLOCK 256
#define CH 256            // gaussians examined per chunk (== BLOCK)
#define QCUT 30.0f        // exp(-15) truncation, total skipped mass < 1e-3

// LDS layout per surviving gaussian (12 floats, 48B, float4-aligned):
// [0]=Sxx [1]=Syy [2]=Szz [3]=2*Sxy [4]=2*Sxz [5]=2*Syz
// [6]=mux [7]=muy [8]=muz [9]=dens [10]=0.25/Sxx [11]=pad

__global__ __launch_bounds__(BLOCK) void vox_kernel(
    const float* __restrict__ means, const float* __restrict__ dens,
    const float* __restrict__ scales, const float* __restrict__ rots,
    float* __restrict__ out, int N)
{
    __shared__ float glds[CH * 12];
    __shared__ int wsum[4];

    const int tid = threadIdx.x;
    const int lane = tid & 63, wave = tid >> 6;
    const int b = blockIdx.x;
    const int tX = b & 7, tY = (b >> 3) & 7, tZ = b >> 6;

    // this thread's 2 x-adjacent voxels inside the tile
    const int x = (tX << 3) + ((tid & 3) << 1);
    const int y = (tY << 3) + ((tid >> 2) & 7);
    const int z = (tZ << 3) + (tid >> 5);
    const float px = (x + 0.5f) * VOXF;
    const float py = (y + 0.5f) * VOXF;
    const float pz = (z + 0.5f) * VOXF;

    // tile sample-center AABB (voxel centers only)
    const float lox = ((tX << 3) + 0.5f) * VOXF, hix = ((tX << 3) + 7.5f) * VOXF;
    const float loy = ((tY << 3) + 0.5f) * VOXF, hiy = ((tY << 3) + 7.5f) * VOXF;
    const float loz = ((tZ << 3) + 0.5f) * VOXF, hiz = ((tZ << 3) + 7.5f) * VOXF;

    float acc0 = 0.f, acc1 = 0.f;

    for (int c0 = 0; c0 < N; c0 += CH) {
        const int gi = c0 + tid;
        const int g = gi < N ? gi : N - 1;

        // ---- block-level cull: sphere(mu, sqrt(QCUT)*max_scale) vs tile AABB ----
        float mx = means[g * 3 + 0], my = means[g * 3 + 1], mz = means[g * 3 + 2];
        float s0 = scales[g * 3 + 0], s1 = scales[g * 3 + 1], s2 = scales[g * 3 + 2];
        float ms = fmaxf(s0, fmaxf(s1, s2));
        float cx = fminf(fmaxf(mx, lox), hix) - mx;
        float cy = fminf(fmaxf(my, loy), hiy) - my;
        float cz = fminf(fmaxf(mz, loz), hiz) - mz;
        float d2 = cx * cx + cy * cy + cz * cz;
        bool keep = (d2 <= QCUT * ms * ms) && (gi < N);

        // ---- stable compaction (deterministic order) ----
        unsigned long long bal = __ballot(keep);
        int pre = __popcll(bal & ((1ull << lane) - 1ull));
        if (lane == 0) wsum[wave] = __popcll(bal);
        __syncthreads();   // #1: wsum visible; prior inner-loop glds reads done
        int base = 0;
        #pragma unroll
        for (int w = 0; w < 4; ++w) base += (w < wave) ? wsum[w] : 0;
        const int cnt = wsum[0] + wsum[1] + wsum[2] + wsum[3];

        if (keep) {
            // quat -> Sigma^-1 only for survivors
            float qw = rots[g * 4 + 0], qx = rots[g * 4 + 1];
            float qy = rots[g * 4 + 2], qz = rots[g * 4 + 3];
            float inm = rsqrtf(qw * qw + qx * qx + qy * qy + qz * qz);
            qw *= inm; qx *= inm; qy *= inm; qz *= inm;
            float r00 = 1.f - 2.f * (qy * qy + qz * qz);
            float r01 = 2.f * (qx * qy - qw * qz);
            float r02 = 2.f * (qx * qz + qw * qy);
            float r10 = 2.f * (qx * qy + qw * qz);
            float r11 = 1.f - 2.f * (qx * qx + qz * qz);
            float r12 = 2.f * (qy * qz - qw * qx);
            float r20 = 2.f * (qx * qz - qw * qy);
            float r21 = 2.f * (qy * qz + qw * qx);
            float r22 = 1.f - 2.f * (qx * qx + qy * qy);
            float i0 = 1.f / (s0 * s0), i1 = 1.f / (s1 * s1), i2 = 1.f / (s2 * s2);
            float A = r00 * r00 * i0 + r01 * r01 * i1 + r02 * r02 * i2;
            float B = r10 * r10 * i0 + r11 * r11 * i1 + r12 * r12 * i2;
            float C = r20 * r20 * i0 + r21 * r21 * i1 + r22 * r22 * i2;
            float D = r00 * r10 * i0 + r01 * r11 * i1 + r02 * r12 * i2;
            float E = r00 * r20 * i0 + r01 * r21 * i1 + r02 * r22 * i2;
            float F = r10 * r20 * i0 + r11 * r21 * i1 + r12 * r22 * i2;
            float4* p = (float4*)&glds[(base + pre) * 12];
            float4 w0; w0.x = A; w0.y = B; w0.z = C; w0.w = 2.f * D;
            float4 w1; w1.x = 2.f * E; w1.y = 2.f * F; w1.z = mx; w1.w = my;
            float4 w2; w2.x = mz; w2.y = dens[g]; w2.z = 0.25f / A; w2.w = 0.f;
            p[0] = w0; p[1] = w1; p[2] = w2;
        }
        __syncthreads();   // #2: compacted list ready

        // ---- accumulate over surviving gaussians ----
        for (int m = 0; m < cnt; ++m) {
            const float4* q4 = (const float4*)&glds[m * 12];
            float4 w0 = q4[0], w1 = q4[1], w2 = q4[2];
            float A = w0.x, B = w0.y, C = w0.z, D2 = w0.w;
            float E2 = w1.x, F2 = w1.y, gmx = w1.z, gmy = w1.w;
            float gmz = w2.x, de = w2.y, i4a = w2.z;

            float dy = py - gmy, dz = pz - gmz;
            float qyz = B * dy * dy + C * dz * dz + F2 * dy * dz;
            float gx = D2 * dy + E2 * dz;
            float qmin = qyz - gx * gx * i4a;   // exact min over continuous dx
            if (__all(qmin > QCUT)) continue;

            float dx0 = px - gmx;
            float dx1 = dx0 + VOXF;
            float q0 = qyz + dx0 * (A * dx0 + gx);
            float q1 = qyz + dx1 * (A * dx1 + gx);
            acc0 += de * __builtin_amdgcn_exp2f(q0 * -0.72134752044f);
            acc1 += de * __builtin_amdgcn_exp2f(q1 * -0.72134752044f);
        }
        __syncthreads();   // protect glds before next chunk's writes (paired w/ #1)
    }

    const int v0 = ((z << 6) + y) * 64 + x;
    float2 r; r.x = acc0; r.y = acc1;
    *(float2*)&out[v0] = r;
}

__global__ void radii_kernel(const float* __restrict__ scales,
                             float* __restrict__ out, int N)
{
    int i = blockIdx.x * 256 + threadIdx.x;
    if (i < N) {
        float s0 = scales[i * 3 + 0], s1 = scales[i * 3 + 1], s2 = scales[i * 3 + 2];
        float m = fmaxf(s0, fmaxf(s1, s2));
        out[NVOX + i] = ceilf(m * 3.0f * 64.0f);
    }
}

extern "C" void kernel_launch(void* const* d_in, const int* in_sizes, int n_in,
                              void* d_out, int out_size, void* d_ws, size_t ws_size,
                              hipStream_t stream)
{
    const float* means  = (const float*)d_in[0];
    const float* dens   = (const float*)d_in[1];
    const float* scales = (const float*)d_in[2];
    const float* rots   = (const float*)d_in[3];
    float* out = (float*)d_out;
    const int N = in_sizes[1];

    vox_kernel<<<512, BLOCK, 0, stream>>>(means, dens, scales, rots, out, N);
    radii_kernel<<<(N + 255) / 256, 256, 0, stream>>>(scales, out, N);
}

// Round 3
// 109.997 us; speedup vs baseline: 3.9525x; 1.1091x over previous
//
#include <hip/hip_runtime.h>

#define GRIDN 64
#define NVOX (GRIDN * GRIDN * GRIDN)
#define VOXF (1.0f / 64.0f)
#define QCUT 30.0f   // exp(-15) truncation; skipped mass < 4096*e^-15 ~ 1e-3

// Table layout per gaussian: 16 floats (64B, one cache line)
//  f4[0] = (Sxx, Syy, Szz, 2*Sxy)      quadratic form (inverse covariance)
//  f4[1] = (2*Sxz, 2*Syz, 0.25/Sxx, density)
//  f4[2] = (mux, muy, muz, 0)
//  f4[3] = (rx, ry, rz, 0)             exact ellipsoid AABB half-widths at q=QCUT

__global__ __launch_bounds__(256) void prep_kernel(
    const float* __restrict__ means, const float* __restrict__ dens,
    const float* __restrict__ scales, const float* __restrict__ rots,
    float* __restrict__ table, float* __restrict__ radii_out, int N)
{
    int i = blockIdx.x * 256 + threadIdx.x;
    if (i >= N) return;

    float qw = rots[i * 4 + 0], qx = rots[i * 4 + 1];
    float qy = rots[i * 4 + 2], qz = rots[i * 4 + 3];
    float inm = rsqrtf(qw * qw + qx * qx + qy * qy + qz * qz);
    qw *= inm; qx *= inm; qy *= inm; qz *= inm;
    float r00 = 1.f - 2.f * (qy * qy + qz * qz);
    float r01 = 2.f * (qx * qy - qw * qz);
    float r02 = 2.f * (qx * qz + qw * qy);
    float r10 = 2.f * (qx * qy + qw * qz);
    float r11 = 1.f - 2.f * (qx * qx + qz * qz);
    float r12 = 2.f * (qy * qz - qw * qx);
    float r20 = 2.f * (qx * qz - qw * qy);
    float r21 = 2.f * (qy * qz + qw * qx);
    float r22 = 1.f - 2.f * (qx * qx + qy * qy);

    float s0 = scales[i * 3 + 0], s1 = scales[i * 3 + 1], s2 = scales[i * 3 + 2];
    float v0 = s0 * s0, v1 = s1 * s1, v2 = s2 * s2;
    float i0 = 1.f / v0, i1 = 1.f / v1, i2 = 1.f / v2;

    // Sinv = R diag(1/s^2) R^T
    float A = r00 * r00 * i0 + r01 * r01 * i1 + r02 * r02 * i2;
    float B = r10 * r10 * i0 + r11 * r11 * i1 + r12 * r12 * i2;
    float C = r20 * r20 * i0 + r21 * r21 * i1 + r22 * r22 * i2;
    float D = r00 * r10 * i0 + r01 * r11 * i1 + r02 * r12 * i2;
    float E = r00 * r20 * i0 + r01 * r21 * i1 + r02 * r22 * i2;
    float F = r10 * r20 * i0 + r11 * r21 * i1 + r12 * r22 * i2;

    // Covariance diagonal (Sigma = R diag(s^2) R^T) -> exact AABB of {q<=QCUT}
    float Cxx = r00 * r00 * v0 + r01 * r01 * v1 + r02 * r02 * v2;
    float Cyy = r10 * r10 * v0 + r11 * r11 * v1 + r12 * r12 * v2;
    float Czz = r20 * r20 * v0 + r21 * r21 * v1 + r22 * r22 * v2;

    float4* T = (float4*)(table + (size_t)i * 16);
    float4 w0; w0.x = A; w0.y = B; w0.z = C; w0.w = 2.f * D;
    float4 w1; w1.x = 2.f * E; w1.y = 2.f * F; w1.z = 0.25f / A; w1.w = dens[i];
    float4 w2; w2.x = means[i * 3 + 0]; w2.y = means[i * 3 + 1]; w2.z = means[i * 3 + 2]; w2.w = 0.f;
    float4 w3; w3.x = sqrtf(QCUT * Cxx); w3.y = sqrtf(QCUT * Cyy); w3.z = sqrtf(QCUT * Czz); w3.w = 0.f;
    T[0] = w0; T[1] = w1; T[2] = w2; T[3] = w3;

    float m = fmaxf(s0, fmaxf(s1, s2));
    radii_out[i] = ceilf(m * 3.0f * 64.0f);
}

// One wave per 8x4x4 voxel tile, VPT=2 along x. No LDS, no barriers.
__global__ __launch_bounds__(64) void vox_kernel(
    const float* __restrict__ table, float* __restrict__ out, int N)
{
    const int lane = threadIdx.x;
    const int b = blockIdx.x;
    const int tX = b & 7, tY = (b >> 3) & 15, tZ = b >> 7;
    const int x = (tX << 3) + ((lane & 3) << 1);
    const int y = (tY << 2) + ((lane >> 2) & 3);
    const int z = (tZ << 2) + (lane >> 4);
    const float px = (x + 0.5f) * VOXF;
    const float py = (y + 0.5f) * VOXF;
    const float pz = (z + 0.5f) * VOXF;

    const float lox = ((tX << 3) + 0.5f) * VOXF, hix = ((tX << 3) + 7.5f) * VOXF;
    const float loy = ((tY << 2) + 0.5f) * VOXF, hiy = ((tY << 2) + 3.5f) * VOXF;
    const float loz = ((tZ << 2) + 0.5f) * VOXF, hiz = ((tZ << 2) + 3.5f) * VOXF;

    float acc0 = 0.f, acc1 = 0.f;

    for (int c0 = 0; c0 < N; c0 += 64) {
        const int gi = c0 + lane;
        const int gc = gi < N ? gi : N - 1;
        const float4* G = (const float4*)(table + (size_t)gc * 16);
        float4 mu = G[2], rr = G[3];
        bool keep = (gi < N)
            && (mu.x + rr.x >= lox) && (mu.x - rr.x <= hix)
            && (mu.y + rr.y >= loy) && (mu.y - rr.y <= hiy)
            && (mu.z + rr.z >= loz) && (mu.z - rr.z <= hiz);

        unsigned long long mask = __ballot(keep);
        if (!mask) continue;

        // iterate survivors in ascending index order (deterministic),
        // 1-deep software prefetch of the next survivor's params
        int g = __builtin_ctzll(mask);
        mask &= mask - 1;
        const float4* P = (const float4*)(table + (size_t)(c0 + g) * 16);
        float4 a0 = P[0], a1 = P[1], a2 = P[2];
        bool more = (mask != 0ull);
        while (true) {
            float4 b0 = a0, b1 = a1, b2 = a2;
            if (more) {
                int gn = __builtin_ctzll(mask);
                mask &= mask - 1;
                const float4* Q = (const float4*)(table + (size_t)(c0 + gn) * 16);
                b0 = Q[0]; b1 = Q[1]; b2 = Q[2];
            }

            float dy = py - a2.y, dz = pz - a2.z;
            float qyz = a0.y * dy * dy + (a0.z * dz + a1.y * dy) * dz;
            float gx = a0.w * dy + a1.x * dz;
            float qmin = qyz - gx * gx * a1.z;   // exact min over continuous dx
            if (!__all(qmin > QCUT)) {
                float dx0 = px - a2.x, dx1 = dx0 + VOXF;
                float q0 = qyz + dx0 * (a0.x * dx0 + gx);
                float q1 = qyz + dx1 * (a0.x * dx1 + gx);
                acc0 += a1.w * __builtin_amdgcn_exp2f(q0 * -0.72134752044f);
                acc1 += a1.w * __builtin_amdgcn_exp2f(q1 * -0.72134752044f);
            }

            if (!more) break;
            a0 = b0; a1 = b1; a2 = b2;
            more = (mask != 0ull);
        }
    }

    const int v = (z << 12) + (y << 6) + x;
    float2 r; r.x = acc0; r.y = acc1;
    *(float2*)&out[v] = r;
}

extern "C" void kernel_launch(void* const* d_in, const int* in_sizes, int n_in,
                              void* d_out, int out_size, void* d_ws, size_t ws_size,
                              hipStream_t stream)
{
    const float* means  = (const float*)d_in[0];
    const float* dens   = (const float*)d_in[1];
    const float* scales = (const float*)d_in[2];
    const float* rots   = (const float*)d_in[3];
    float* out = (float*)d_out;
    float* table = (float*)d_ws;   // N*64 bytes
    const int N = in_sizes[1];

    prep_kernel<<<(N + 255) / 256, 256, 0, stream>>>(means, dens, scales, rots,
                                                     table, out + NVOX, N);
    vox_kernel<<<2048, 64, 0, stream>>>(table, out, N);
}

// Round 4
// 100.870 us; speedup vs baseline: 4.3102x; 1.0905x over previous
//
#include <hip/hip_runtime.h>

#define GRIDN 64
#define NVOX (GRIDN * GRIDN * GRIDN)
#define VOXF (1.0f / 64.0f)
#define QCUT 30.0f              // exp(-15) truncation; skipped mass < 4096*e^-15 ~ 1e-3
#define EXPSCL (-0.72134752044f) // -0.5 * log2(e); folded into table coefficients
#define SKIPTH (-21.6404256f)    // QCUT * EXPSCL  (q' < this  <=>  q > QCUT)

// Table layout per gaussian: 16 floats (64B, one cache line). Quadratic-form
// coefficients are PRE-SCALED by EXPSCL so exp2(q') is used directly.
//  f4[0] = (A', B', C', 2D')      scaled inverse covariance
//  f4[1] = (2E', 2F', 0.25/A', density)
//  f4[2] = (mux, muy, muz, 0)
//  f4[3] = (rx, ry, rz, 0)        exact ellipsoid AABB half-widths at q=QCUT

__global__ __launch_bounds__(256) void prep_kernel(
    const float* __restrict__ means, const float* __restrict__ dens,
    const float* __restrict__ scales, const float* __restrict__ rots,
    float* __restrict__ table, float* __restrict__ radii_out, int N)
{
    int i = blockIdx.x * 256 + threadIdx.x;
    if (i >= N) return;

    float qw = rots[i * 4 + 0], qx = rots[i * 4 + 1];
    float qy = rots[i * 4 + 2], qz = rots[i * 4 + 3];
    float inm = rsqrtf(qw * qw + qx * qx + qy * qy + qz * qz);
    qw *= inm; qx *= inm; qy *= inm; qz *= inm;
    float r00 = 1.f - 2.f * (qy * qy + qz * qz);
    float r01 = 2.f * (qx * qy - qw * qz);
    float r02 = 2.f * (qx * qz + qw * qy);
    float r10 = 2.f * (qx * qy + qw * qz);
    float r11 = 1.f - 2.f * (qx * qx + qz * qz);
    float r12 = 2.f * (qy * qz - qw * qx);
    float r20 = 2.f * (qx * qz - qw * qy);
    float r21 = 2.f * (qy * qz + qw * qx);
    float r22 = 1.f - 2.f * (qx * qx + qy * qy);

    float s0 = scales[i * 3 + 0], s1 = scales[i * 3 + 1], s2 = scales[i * 3 + 2];
    float v0 = s0 * s0, v1 = s1 * s1, v2 = s2 * s2;
    float i0 = 1.f / v0, i1 = 1.f / v1, i2 = 1.f / v2;

    // Sinv = R diag(1/s^2) R^T, then scale by EXPSCL
    float A = (r00 * r00 * i0 + r01 * r01 * i1 + r02 * r02 * i2) * EXPSCL;
    float B = (r10 * r10 * i0 + r11 * r11 * i1 + r12 * r12 * i2) * EXPSCL;
    float C = (r20 * r20 * i0 + r21 * r21 * i1 + r22 * r22 * i2) * EXPSCL;
    float D = (r00 * r10 * i0 + r01 * r11 * i1 + r02 * r12 * i2) * EXPSCL;
    float E = (r00 * r20 * i0 + r01 * r21 * i1 + r02 * r22 * i2) * EXPSCL;
    float F = (r10 * r20 * i0 + r11 * r21 * i1 + r12 * r22 * i2) * EXPSCL;

    // Covariance diagonal (Sigma = R diag(s^2) R^T) -> exact AABB of {q<=QCUT}
    float Cxx = r00 * r00 * v0 + r01 * r01 * v1 + r02 * r02 * v2;
    float Cyy = r10 * r10 * v0 + r11 * r11 * v1 + r12 * r12 * v2;
    float Czz = r20 * r20 * v0 + r21 * r21 * v1 + r22 * r22 * v2;

    float4* T = (float4*)(table + (size_t)i * 16);
    float4 w0; w0.x = A; w0.y = B; w0.z = C; w0.w = 2.f * D;
    float4 w1; w1.x = 2.f * E; w1.y = 2.f * F; w1.z = 0.25f / A; w1.w = dens[i];
    float4 w2; w2.x = means[i * 3 + 0]; w2.y = means[i * 3 + 1]; w2.z = means[i * 3 + 2]; w2.w = 0.f;
    float4 w3; w3.x = sqrtf(QCUT * Cxx); w3.y = sqrtf(QCUT * Cyy); w3.z = sqrtf(QCUT * Czz); w3.w = 0.f;
    T[0] = w0; T[1] = w1; T[2] = w2; T[3] = w3;

    float m = fmaxf(s0, fmaxf(s1, s2));
    radii_out[i] = ceilf(m * 3.0f * 64.0f);
}

// broadcast lane g's register to all lanes (v_readlane, no memory)
__device__ __forceinline__ float bcast(float v, int l) {
    return __uint_as_float(__builtin_amdgcn_readlane(__float_as_uint(v), (unsigned)l));
}

// One wave per 8x4x4 voxel tile, VPT=2 along x. No LDS, no barriers,
// no memory ops in the survivor loop (lane-resident params + readlane).
__global__ __launch_bounds__(64) void vox_kernel(
    const float* __restrict__ table, float* __restrict__ out, int N)
{
    const int lane = threadIdx.x;
    const int b = blockIdx.x;
    const int tX = b & 7, tY = (b >> 3) & 15, tZ = b >> 7;
    const int x = (tX << 3) + ((lane & 3) << 1);
    const int y = (tY << 2) + ((lane >> 2) & 3);
    const int z = (tZ << 2) + (lane >> 4);
    const float px = (x + 0.5f) * VOXF;
    const float py = (y + 0.5f) * VOXF;
    const float pz = (z + 0.5f) * VOXF;

    const float lox = ((tX << 3) + 0.5f) * VOXF, hix = ((tX << 3) + 7.5f) * VOXF;
    const float loy = ((tY << 2) + 0.5f) * VOXF, hiy = ((tY << 2) + 3.5f) * VOXF;
    const float loz = ((tZ << 2) + 0.5f) * VOXF, hiz = ((tZ << 2) + 3.5f) * VOXF;

    float acc0 = 0.f, acc1 = 0.f;

    for (int c0 = 0; c0 < N; c0 += 64) {
        const int gi = c0 + lane;
        const int gc = gi < N ? gi : N - 1;
        const float4* G = (const float4*)(table + (size_t)gc * 16);
        // each lane holds its gaussian's full record; 4 independent dwordx4,
        // coalesced, latency pipelined across the AABB test below
        float4 r0 = G[0], r1 = G[1], r2 = G[2], rr = G[3];
        bool keep = (gi < N)
            && (r2.x + rr.x >= lox) && (r2.x - rr.x <= hix)
            && (r2.y + rr.y >= loy) && (r2.y - rr.y <= hiy)
            && (r2.z + rr.z >= loz) && (r2.z - rr.z <= hiz);

        unsigned long long mask = __ballot(keep);
        while (mask) {
            const int g = (int)__builtin_ctzll(mask);
            mask &= mask - 1;
            // broadcast survivor params from owning lane's registers
            float A  = bcast(r0.x, g), Bq = bcast(r0.y, g);
            float Cq = bcast(r0.z, g), D2 = bcast(r0.w, g);
            float E2 = bcast(r1.x, g), F2 = bcast(r1.y, g);
            float i4a = bcast(r1.z, g);
            float mx = bcast(r2.x, g), my = bcast(r2.y, g), mz = bcast(r2.z, g);

            float dy = py - my, dz = pz - mz;
            float u   = Cq * dz + F2 * dy;
            float qyz = (Bq * dy) * dy + u * dz;
            float gx  = D2 * dy + E2 * dz;
            float qmin = qyz - (gx * gx) * i4a;  // scaled-min over continuous dx
            if (__all(qmin < SKIPTH)) continue;  // all q > QCUT

            float de = bcast(r1.w, g);
            float dx0 = px - mx, dx1 = dx0 + VOXF;
            float q0 = qyz + dx0 * (A * dx0 + gx);
            float q1 = qyz + dx1 * (A * dx1 + gx);
            acc0 += de * __builtin_amdgcn_exp2f(q0);
            acc1 += de * __builtin_amdgcn_exp2f(q1);
        }
    }

    const int v = (z << 12) + (y << 6) + x;
    float2 r; r.x = acc0; r.y = acc1;
    *(float2*)&out[v] = r;
}

extern "C" void kernel_launch(void* const* d_in, const int* in_sizes, int n_in,
                              void* d_out, int out_size, void* d_ws, size_t ws_size,
                              hipStream_t stream)
{
    const float* means  = (const float*)d_in[0];
    const float* dens   = (const float*)d_in[1];
    const float* scales = (const float*)d_in[2];
    const float* rots   = (const float*)d_in[3];
    float* out = (float*)d_out;
    float* table = (float*)d_ws;   // N*64 bytes
    const int N = in_sizes[1];

    prep_kernel<<<(N + 255) / 256, 256, 0, stream>>>(means, dens, scales, rots,
                                                     table, out + NVOX, N);
    vox_kernel<<<2048, 64, 0, stream>>>(table, out, N);
}

// Round 5
// 77.194 us; speedup vs baseline: 5.6321x; 1.3067x over previous
//
#include <hip/hip_runtime.h>

#define GRIDN 64
#define NVOX (GRIDN * GRIDN * GRIDN)
#define VOXF (1.0f / 64.0f)
#define QCUT 30.0f              // exp(-15) truncation; skipped mass < 4096*e^-15 ~ 1e-3
#define EXPSCL (-0.72134752044f) // -0.5 * log2(e); folded into table coefficients
#define SKIPTH (-21.6404256f)    // QCUT * EXPSCL  (q' < this  <=>  q > QCUT)

// Table layout per gaussian: 16 floats (64B, one cache line). Quadratic-form
// coefficients are PRE-SCALED by EXPSCL so exp2(q') is used directly.
//  f4[0] = (A', B', C', 2D')      scaled inverse covariance
//  f4[1] = (2E', 2F', 0.25/A', density)
//  f4[2] = (mux, muy, muz, 0)
//  f4[3] = (rx, ry, rz, 0)        exact ellipsoid AABB half-widths at q=QCUT

__global__ __launch_bounds__(256) void prep_kernel(
    const float* __restrict__ means, const float* __restrict__ dens,
    const float* __restrict__ scales, const float* __restrict__ rots,
    float* __restrict__ table, float* __restrict__ radii_out, int N)
{
    int i = blockIdx.x * 256 + threadIdx.x;
    if (i >= N) return;

    float qw = rots[i * 4 + 0], qx = rots[i * 4 + 1];
    float qy = rots[i * 4 + 2], qz = rots[i * 4 + 3];
    float inm = rsqrtf(qw * qw + qx * qx + qy * qy + qz * qz);
    qw *= inm; qx *= inm; qy *= inm; qz *= inm;
    float r00 = 1.f - 2.f * (qy * qy + qz * qz);
    float r01 = 2.f * (qx * qy - qw * qz);
    float r02 = 2.f * (qx * qz + qw * qy);
    float r10 = 2.f * (qx * qy + qw * qz);
    float r11 = 1.f - 2.f * (qx * qx + qz * qz);
    float r12 = 2.f * (qy * qz - qw * qx);
    float r20 = 2.f * (qx * qz - qw * qy);
    float r21 = 2.f * (qy * qz + qw * qx);
    float r22 = 1.f - 2.f * (qx * qx + qy * qy);

    float s0 = scales[i * 3 + 0], s1 = scales[i * 3 + 1], s2 = scales[i * 3 + 2];
    float v0 = s0 * s0, v1 = s1 * s1, v2 = s2 * s2;
    float i0 = 1.f / v0, i1 = 1.f / v1, i2 = 1.f / v2;

    // Sinv = R diag(1/s^2) R^T, then scale by EXPSCL
    float A = (r00 * r00 * i0 + r01 * r01 * i1 + r02 * r02 * i2) * EXPSCL;
    float B = (r10 * r10 * i0 + r11 * r11 * i1 + r12 * r12 * i2) * EXPSCL;
    float C = (r20 * r20 * i0 + r21 * r21 * i1 + r22 * r22 * i2) * EXPSCL;
    float D = (r00 * r10 * i0 + r01 * r11 * i1 + r02 * r12 * i2) * EXPSCL;
    float E = (r00 * r20 * i0 + r01 * r21 * i1 + r02 * r22 * i2) * EXPSCL;
    float F = (r10 * r20 * i0 + r11 * r21 * i1 + r12 * r22 * i2) * EXPSCL;

    // Covariance diagonal (Sigma = R diag(s^2) R^T) -> exact AABB of {q<=QCUT}
    float Cxx = r00 * r00 * v0 + r01 * r01 * v1 + r02 * r02 * v2;
    float Cyy = r10 * r10 * v0 + r11 * r11 * v1 + r12 * r12 * v2;
    float Czz = r20 * r20 * v0 + r21 * r21 * v1 + r22 * r22 * v2;

    float4* T = (float4*)(table + (size_t)i * 16);
    float4 w0; w0.x = A; w0.y = B; w0.z = C; w0.w = 2.f * D;
    float4 w1; w1.x = 2.f * E; w1.y = 2.f * F; w1.z = 0.25f / A; w1.w = dens[i];
    float4 w2; w2.x = means[i * 3 + 0]; w2.y = means[i * 3 + 1]; w2.z = means[i * 3 + 2]; w2.w = 0.f;
    float4 w3; w3.x = sqrtf(QCUT * Cxx); w3.y = sqrtf(QCUT * Cyy); w3.z = sqrtf(QCUT * Czz); w3.w = 0.f;
    T[0] = w0; T[1] = w1; T[2] = w2; T[3] = w3;

    float m = fmaxf(s0, fmaxf(s1, s2));
    radii_out[i] = ceilf(m * 3.0f * 64.0f);
}

// broadcast lane g's register to all lanes (v_readlane, no memory)
__device__ __forceinline__ float bcast(float v, int l) {
    return __uint_as_float(__builtin_amdgcn_readlane(__float_as_uint(v), (unsigned)l));
}

// 4 waves per block, ALL on the same 8x4x4 voxel tile (VPT=2 along x).
// Wave w processes gaussian chunks w, w+4, w+8, ... (disjoint quarters);
// partials combine through LDS in fixed wave order -> deterministic.
__global__ __launch_bounds__(256) void vox_kernel(
    const float* __restrict__ table, float* __restrict__ out, int N)
{
    __shared__ float2 plds[4][64];

    const int tid = threadIdx.x;
    const int lane = tid & 63, wave = tid >> 6;
    const int b = blockIdx.x;
    const int tX = b & 7, tY = (b >> 3) & 15, tZ = b >> 7;
    const int x = (tX << 3) + ((lane & 3) << 1);
    const int y = (tY << 2) + ((lane >> 2) & 3);
    const int z = (tZ << 2) + (lane >> 4);
    const float px = (x + 0.5f) * VOXF;
    const float py = (y + 0.5f) * VOXF;
    const float pz = (z + 0.5f) * VOXF;

    const float lox = ((tX << 3) + 0.5f) * VOXF, hix = ((tX << 3) + 7.5f) * VOXF;
    const float loy = ((tY << 2) + 0.5f) * VOXF, hiy = ((tY << 2) + 3.5f) * VOXF;
    const float loz = ((tZ << 2) + 0.5f) * VOXF, hiz = ((tZ << 2) + 3.5f) * VOXF;

    float acc0 = 0.f, acc1 = 0.f;

    const int nch = (N + 63) >> 6;
    for (int c = wave; c < nch; c += 4) {
        const int c0 = c << 6;
        const int gi = c0 + lane;
        const int gc = gi < N ? gi : N - 1;
        const float4* G = (const float4*)(table + (size_t)gc * 16);
        // each lane holds its gaussian's full record; 4 independent dwordx4,
        // coalesced, latency pipelined across the AABB test below
        float4 r0 = G[0], r1 = G[1], r2 = G[2], rr = G[3];
        bool keep = (gi < N)
            && (r2.x + rr.x >= lox) && (r2.x - rr.x <= hix)
            && (r2.y + rr.y >= loy) && (r2.y - rr.y <= hiy)
            && (r2.z + rr.z >= loz) && (r2.z - rr.z <= hiz);

        unsigned long long mask = __ballot(keep);
        while (mask) {
            const int g = (int)__builtin_ctzll(mask);
            mask &= mask - 1;
            // broadcast survivor params from owning lane's registers
            float A  = bcast(r0.x, g), Bq = bcast(r0.y, g);
            float Cq = bcast(r0.z, g), D2 = bcast(r0.w, g);
            float E2 = bcast(r1.x, g), F2 = bcast(r1.y, g);
            float i4a = bcast(r1.z, g);
            float mx = bcast(r2.x, g), my = bcast(r2.y, g), mz = bcast(r2.z, g);

            float dy = py - my, dz = pz - mz;
            float u   = Cq * dz + F2 * dy;
            float qyz = (Bq * dy) * dy + u * dz;
            float gx  = D2 * dy + E2 * dz;
            float qmin = qyz - (gx * gx) * i4a;  // scaled-min over continuous dx
            if (__all(qmin < SKIPTH)) continue;  // all q > QCUT

            float de = bcast(r1.w, g);
            float dx0 = px - mx, dx1 = dx0 + VOXF;
            float q0 = qyz + dx0 * (A * dx0 + gx);
            float q1 = qyz + dx1 * (A * dx1 + gx);
            acc0 += de * __builtin_amdgcn_exp2f(q0);
            acc1 += de * __builtin_amdgcn_exp2f(q1);
        }
    }

    float2 p; p.x = acc0; p.y = acc1;
    plds[wave][lane] = p;
    __syncthreads();

    if (wave == 0) {
        float2 p0 = plds[0][lane], p1 = plds[1][lane];
        float2 p2 = plds[2][lane], p3 = plds[3][lane];
        float2 r;
        r.x = ((p0.x + p1.x) + p2.x) + p3.x;   // fixed order: deterministic
        r.y = ((p0.y + p1.y) + p2.y) + p3.y;
        const int v = (z << 12) + (y << 6) + x;
        *(float2*)&out[v] = r;
    }
}

extern "C" void kernel_launch(void* const* d_in, const int* in_sizes, int n_in,
                              void* d_out, int out_size, void* d_ws, size_t ws_size,
                              hipStream_t stream)
{
    const float* means  = (const float*)d_in[0];
    const float* dens   = (const float*)d_in[1];
    const float* scales = (const float*)d_in[2];
    const float* rots   = (const float*)d_in[3];
    float* out = (float*)d_out;
    float* table = (float*)d_ws;   // N*64 bytes
    const int N = in_sizes[1];

    prep_kernel<<<(N + 255) / 256, 256, 0, stream>>>(means, dens, scales, rots,
                                                     table, out + NVOX, N);
    vox_kernel<<<2048, 256, 0, stream>>>(table, out, N);
}

// Round 6
// 50.816 us; speedup vs baseline: 8.5556x; 1.5191x over previous
//
#include <hip/hip_runtime.h>

#define GRIDN 64
#define NVOX (GRIDN * GRIDN * GRIDN)
#define VOXF (1.0f / 64.0f)
#define QCUT 30.0f              // exp(-15) truncation; skipped mass < 4096*e^-15 ~ 1e-3
#define EXPSCL (-0.72134752044f) // -0.5 * log2(e); folded into table coefficients
#define SKIPTH (-21.6404256f)    // QCUT * EXPSCL  (q' < this  <=>  q > QCUT)

// Table layout per gaussian: 16 floats (64B, one cache line). Quadratic-form
// coefficients are PRE-SCALED by EXPSCL so exp2(q') is used directly.
//  f4[0] = (A', B', C', 2D')      scaled inverse covariance
//  f4[1] = (2E', 2F', 0.25/A', density)
//  f4[2] = (mux, muy, muz, 0)
//  f4[3] = (rx, ry, rz, 0)        exact ellipsoid AABB half-widths at q=QCUT

__global__ __launch_bounds__(256) void prep_kernel(
    const float* __restrict__ means, const float* __restrict__ dens,
    const float* __restrict__ scales, const float* __restrict__ rots,
    float* __restrict__ table, float* __restrict__ radii_out, int N)
{
    int i = blockIdx.x * 256 + threadIdx.x;
    if (i >= N) return;

    float qw = rots[i * 4 + 0], qx = rots[i * 4 + 1];
    float qy = rots[i * 4 + 2], qz = rots[i * 4 + 3];
    float inm = rsqrtf(qw * qw + qx * qx + qy * qy + qz * qz);
    qw *= inm; qx *= inm; qy *= inm; qz *= inm;
    float r00 = 1.f - 2.f * (qy * qy + qz * qz);
    float r01 = 2.f * (qx * qy - qw * qz);
    float r02 = 2.f * (qx * qz + qw * qy);
    float r10 = 2.f * (qx * qy + qw * qz);
    float r11 = 1.f - 2.f * (qx * qx + qz * qz);
    float r12 = 2.f * (qy * qz - qw * qx);
    float r20 = 2.f * (qx * qz - qw * qy);
    float r21 = 2.f * (qy * qz + qw * qx);
    float r22 = 1.f - 2.f * (qx * qx + qy * qy);

    float s0 = scales[i * 3 + 0], s1 = scales[i * 3 + 1], s2 = scales[i * 3 + 2];
    float v0 = s0 * s0, v1 = s1 * s1, v2 = s2 * s2;
    float i0 = 1.f / v0, i1 = 1.f / v1, i2 = 1.f / v2;

    // Sinv = R diag(1/s^2) R^T, then scale by EXPSCL
    float A = (r00 * r00 * i0 + r01 * r01 * i1 + r02 * r02 * i2) * EXPSCL;
    float B = (r10 * r10 * i0 + r11 * r11 * i1 + r12 * r12 * i2) * EXPSCL;
    float C = (r20 * r20 * i0 + r21 * r21 * i1 + r22 * r22 * i2) * EXPSCL;
    float D = (r00 * r10 * i0 + r01 * r11 * i1 + r02 * r12 * i2) * EXPSCL;
    float E = (r00 * r20 * i0 + r01 * r21 * i1 + r02 * r22 * i2) * EXPSCL;
    float F = (r10 * r20 * i0 + r11 * r21 * i1 + r12 * r22 * i2) * EXPSCL;

    // Covariance diagonal (Sigma = R diag(s^2) R^T) -> exact AABB of {q<=QCUT}
    float Cxx = r00 * r00 * v0 + r01 * r01 * v1 + r02 * r02 * v2;
    float Cyy = r10 * r10 * v0 + r11 * r11 * v1 + r12 * r12 * v2;
    float Czz = r20 * r20 * v0 + r21 * r21 * v1 + r22 * r22 * v2;

    float4* T = (float4*)(table + (size_t)i * 16);
    float4 w0; w0.x = A; w0.y = B; w0.z = C; w0.w = 2.f * D;
    float4 w1; w1.x = 2.f * E; w1.y = 2.f * F; w1.z = 0.25f / A; w1.w = dens[i];
    float4 w2; w2.x = means[i * 3 + 0]; w2.y = means[i * 3 + 1]; w2.z = means[i * 3 + 2]; w2.w = 0.f;
    float4 w3; w3.x = sqrtf(QCUT * Cxx); w3.y = sqrtf(QCUT * Cyy); w3.z = sqrtf(QCUT * Czz); w3.w = 0.f;
    T[0] = w0; T[1] = w1; T[2] = w2; T[3] = w3;

    float m = fmaxf(s0, fmaxf(s1, s2));
    radii_out[i] = ceilf(m * 3.0f * 64.0f);
}

// 8 waves per block, ALL on the same 16x4x4 voxel tile (VPT=4 along x).
// Wave w processes gaussian chunks w, w+8, ... (disjoint eighths); partials
// combine through LDS in fixed wave order -> deterministic.
// Survivor params come via wave-uniform s_load (scalar pipe), 1-deep prefetch.
__global__ __launch_bounds__(512) void vox_kernel(
    const float* __restrict__ table, float* __restrict__ out, int N)
{
    __shared__ float4 plds[8][64];

    const int tid = threadIdx.x;
    const int lane = tid & 63, wave = tid >> 6;
    const int b = blockIdx.x;
    const int tX = b & 3, tY = (b >> 2) & 15, tZ = b >> 6;
    const int x = (tX << 4) + ((lane & 3) << 2);   // first of this lane's 4 x-voxels
    const int y = (tY << 2) + ((lane >> 2) & 3);
    const int z = (tZ << 2) + (lane >> 4);
    const float px = (x + 0.5f) * VOXF;
    const float py = (y + 0.5f) * VOXF;
    const float pz = (z + 0.5f) * VOXF;

    const float lox = ((tX << 4) + 0.5f) * VOXF, hix = ((tX << 4) + 15.5f) * VOXF;
    const float loy = ((tY << 2) + 0.5f) * VOXF, hiy = ((tY << 2) + 3.5f) * VOXF;
    const float loz = ((tZ << 2) + 0.5f) * VOXF, hiz = ((tZ << 2) + 3.5f) * VOXF;

    float4 acc; acc.x = 0.f; acc.y = 0.f; acc.z = 0.f; acc.w = 0.f;

    const int nch = (N + 63) >> 6;
    for (int c = wave; c < nch; c += 8) {
        const int c0 = c << 6;
        const int gi = c0 + lane;
        const int gc = gi < N ? gi : N - 1;
        const float4* G = (const float4*)(table + (size_t)gc * 16);
        // cull needs only mu + AABB radii: 2 coalesced dwordx4 per lane
        float4 mu = G[2], rr = G[3];
        bool keep = (gi < N)
            && (mu.x + rr.x >= lox) && (mu.x - rr.x <= hix)
            && (mu.y + rr.y >= loy) && (mu.y - rr.y <= hiy)
            && (mu.z + rr.z >= loz) && (mu.z - rr.z <= hiz);

        unsigned long long mask = __ballot(keep);
        if (!mask) continue;

        // survivor loop: wave-uniform scalar loads, 1-deep prefetch
        int g = (int)__builtin_ctzll(mask);
        mask &= mask - 1;
        int u = __builtin_amdgcn_readfirstlane(c0 + g);
        const float4* P = (const float4*)(table + (size_t)u * 16);
        float4 a0 = P[0], a1 = P[1], a2 = P[2];
        bool more = (mask != 0ull);
        while (true) {
            float4 b0 = a0, b1 = a1, b2 = a2;
            if (more) {
                int gn = (int)__builtin_ctzll(mask);
                mask &= mask - 1;
                int un = __builtin_amdgcn_readfirstlane(c0 + gn);
                const float4* Q = (const float4*)(table + (size_t)un * 16);
                b0 = Q[0]; b1 = Q[1]; b2 = Q[2];
            }

            // all a* operands are SGPRs: <=1 SGPR per VALU instr holds throughout
            float dy = py - a2.y, dz = pz - a2.z;
            float qyz = (a0.y * dy) * dy + (a0.z * dz + a1.y * dy) * dz;
            float gx  = a0.w * dy + a1.x * dz;
            float qmin = qyz - (gx * gx) * a1.z;   // scaled-min over continuous dx
            if (!__all(qmin < SKIPTH)) {           // some lane's strip reaches q < QCUT
                float dx0 = px - a2.x;
                float dx1 = dx0 + VOXF;
                float dx2 = dx0 + 2.0f * VOXF;
                float dx3 = dx0 + 3.0f * VOXF;
                float q0 = qyz + dx0 * (a0.x * dx0 + gx);
                float q1 = qyz + dx1 * (a0.x * dx1 + gx);
                float q2 = qyz + dx2 * (a0.x * dx2 + gx);
                float q3 = qyz + dx3 * (a0.x * dx3 + gx);
                float de = a1.w;
                acc.x += de * __builtin_amdgcn_exp2f(q0);
                acc.y += de * __builtin_amdgcn_exp2f(q1);
                acc.z += de * __builtin_amdgcn_exp2f(q2);
                acc.w += de * __builtin_amdgcn_exp2f(q3);
            }

            if (!more) break;
            a0 = b0; a1 = b1; a2 = b2;
            more = (mask != 0ull);
        }
    }

    plds[wave][lane] = acc;
    __syncthreads();

    if (wave == 0) {
        float4 r = plds[0][lane];
        #pragma unroll
        for (int w = 1; w < 8; ++w) {       // fixed order: deterministic
            float4 p = plds[w][lane];
            r.x += p.x; r.y += p.y; r.z += p.z; r.w += p.w;
        }
        const int v = (z << 12) + (y << 6) + x;
        *(float4*)&out[v] = r;
    }
}

extern "C" void kernel_launch(void* const* d_in, const int* in_sizes, int n_in,
                              void* d_out, int out_size, void* d_ws, size_t ws_size,
                              hipStream_t stream)
{
    const float* means  = (const float*)d_in[0];
    const float* dens   = (const float*)d_in[1];
    const float* scales = (const float*)d_in[2];
    const float* rots   = (const float*)d_in[3];
    float* out = (float*)d_out;
    float* table = (float*)d_ws;   // N*64 bytes
    const int N = in_sizes[1];

    prep_kernel<<<(N + 255) / 256, 256, 0, stream>>>(means, dens, scales, rots,
                                                     table, out + NVOX, N);
    vox_kernel<<<1024, 512, 0, stream>>>(table, out, N);
}

// Round 7
// 42.132 us; speedup vs baseline: 10.3191x; 1.2061x over previous
//
#include <hip/hip_runtime.h>

#define GRIDN 64
#define NVOX (GRIDN * GRIDN * GRIDN)
#define VOXF (1.0f / 64.0f)
#define QCUT 20.0f               // exp(-10) truncation; added error ~3e-3 << 0.24 threshold
#define EXPSCL (-0.72134752044f) // -0.5 * log2(e); folded into table coefficients
#define SKIPTH (QCUT * EXPSCL)   // q' < this  <=>  q > QCUT

// Table layout per gaussian: 16 floats (64B, one cache line). Quadratic-form
// coefficients are PRE-SCALED by EXPSCL so exp2(q') is used directly.
//  f4[0] = (A', B', C', 2D')      scaled inverse covariance
//  f4[1] = (2E', 2F', 0.25/A', density)
//  f4[2] = (mux, muy, muz, 0)
//  f4[3] = (rx, ry, rz, 0)        exact ellipsoid AABB half-widths at q=QCUT

__global__ __launch_bounds__(256) void prep_kernel(
    const float* __restrict__ means, const float* __restrict__ dens,
    const float* __restrict__ scales, const float* __restrict__ rots,
    float* __restrict__ table, float* __restrict__ radii_out, int N)
{
    int i = blockIdx.x * 256 + threadIdx.x;
    if (i >= N) return;

    float qw = rots[i * 4 + 0], qx = rots[i * 4 + 1];
    float qy = rots[i * 4 + 2], qz = rots[i * 4 + 3];
    float inm = rsqrtf(qw * qw + qx * qx + qy * qy + qz * qz);
    qw *= inm; qx *= inm; qy *= inm; qz *= inm;
    float r00 = 1.f - 2.f * (qy * qy + qz * qz);
    float r01 = 2.f * (qx * qy - qw * qz);
    float r02 = 2.f * (qx * qz + qw * qy);
    float r10 = 2.f * (qx * qy + qw * qz);
    float r11 = 1.f - 2.f * (qx * qx + qz * qz);
    float r12 = 2.f * (qy * qz - qw * qx);
    float r20 = 2.f * (qx * qz - qw * qy);
    float r21 = 2.f * (qy * qz + qw * qx);
    float r22 = 1.f - 2.f * (qx * qx + qy * qy);

    float s0 = scales[i * 3 + 0], s1 = scales[i * 3 + 1], s2 = scales[i * 3 + 2];
    float v0 = s0 * s0, v1 = s1 * s1, v2 = s2 * s2;
    float i0 = 1.f / v0, i1 = 1.f / v1, i2 = 1.f / v2;

    // Sinv = R diag(1/s^2) R^T, then scale by EXPSCL
    float A = (r00 * r00 * i0 + r01 * r01 * i1 + r02 * r02 * i2) * EXPSCL;
    float B = (r10 * r10 * i0 + r11 * r11 * i1 + r12 * r12 * i2) * EXPSCL;
    float C = (r20 * r20 * i0 + r21 * r21 * i1 + r22 * r22 * i2) * EXPSCL;
    float D = (r00 * r10 * i0 + r01 * r11 * i1 + r02 * r12 * i2) * EXPSCL;
    float E = (r00 * r20 * i0 + r01 * r21 * i1 + r02 * r22 * i2) * EXPSCL;
    float F = (r10 * r20 * i0 + r11 * r21 * i1 + r12 * r22 * i2) * EXPSCL;

    // Covariance diagonal (Sigma = R diag(s^2) R^T) -> exact AABB of {q<=QCUT}
    float Cxx = r00 * r00 * v0 + r01 * r01 * v1 + r02 * r02 * v2;
    float Cyy = r10 * r10 * v0 + r11 * r11 * v1 + r12 * r12 * v2;
    float Czz = r20 * r20 * v0 + r21 * r21 * v1 + r22 * r22 * v2;

    float4* T = (float4*)(table + (size_t)i * 16);
    float4 w0; w0.x = A; w0.y = B; w0.z = C; w0.w = 2.f * D;
    float4 w1; w1.x = 2.f * E; w1.y = 2.f * F; w1.z = 0.25f / A; w1.w = dens[i];
    float4 w2; w2.x = means[i * 3 + 0]; w2.y = means[i * 3 + 1]; w2.z = means[i * 3 + 2]; w2.w = 0.f;
    float4 w3; w3.x = sqrtf(QCUT * Cxx); w3.y = sqrtf(QCUT * Cyy); w3.z = sqrtf(QCUT * Czz); w3.w = 0.f;
    T[0] = w0; T[1] = w1; T[2] = w2; T[3] = w3;

    float m = fmaxf(s0, fmaxf(s1, s2));
    radii_out[i] = ceilf(m * 3.0f * 64.0f);
}

// 8 waves per block, ALL on the same 8x8x4 voxel tile (VPT=4 along x).
// Wave w processes gaussian chunks w, w+8, ... (disjoint eighths); partials
// combine through LDS in fixed wave order -> deterministic.
// Survivor params via wave-uniform s_load (scalar pipe), 2-deep prefetch.
__global__ __launch_bounds__(512) void vox_kernel(
    const float* __restrict__ table, float* __restrict__ out, int N)
{
    __shared__ float4 plds[8][64];

    const int tid = threadIdx.x;
    const int lane = tid & 63, wave = tid >> 6;
    // bijective scatter (gcd(421,1024)=1): spatially adjacent heavy tiles
    // get far-apart block IDs -> per-CU load averages out
    const int t = (blockIdx.x * 421) & 1023;
    const int tX = t & 7, tY = (t >> 3) & 7, tZ = t >> 6;   // 8 x 8 x 16 tiles
    const int x = (tX << 3) + ((lane & 1) << 2);   // first of this lane's 4 x-voxels
    const int y = (tY << 3) + ((lane >> 1) & 7);
    const int z = (tZ << 2) + (lane >> 4);
    const float px = (x + 0.5f) * VOXF;
    const float py = (y + 0.5f) * VOXF;
    const float pz = (z + 0.5f) * VOXF;

    const float lox = ((tX << 3) + 0.5f) * VOXF, hix = ((tX << 3) + 7.5f) * VOXF;
    const float loy = ((tY << 3) + 0.5f) * VOXF, hiy = ((tY << 3) + 7.5f) * VOXF;
    const float loz = ((tZ << 2) + 0.5f) * VOXF, hiz = ((tZ << 2) + 3.5f) * VOXF;

    float4 acc; acc.x = 0.f; acc.y = 0.f; acc.z = 0.f; acc.w = 0.f;

    const int nch = (N + 63) >> 6;
    for (int c = wave; c < nch; c += 8) {
        const int c0 = c << 6;
        const int gi = c0 + lane;
        const int gc = gi < N ? gi : N - 1;
        const float4* G = (const float4*)(table + (size_t)gc * 16);
        // cull needs only mu + AABB radii: 2 coalesced dwordx4 per lane
        float4 mu = G[2], rr = G[3];
        bool keep = (gi < N)
            && (mu.x + rr.x >= lox) && (mu.x - rr.x <= hix)
            && (mu.y + rr.y >= loy) && (mu.y - rr.y <= hiy)
            && (mu.z + rr.z >= loz) && (mu.z - rr.z <= hiz);

        unsigned long long mask = __ballot(keep);
        if (!mask) continue;

        // survivor loop: wave-uniform scalar loads, 2-deep prefetch
        int g0 = (int)__builtin_ctzll(mask); mask &= mask - 1;
        int u0 = __builtin_amdgcn_readfirstlane(c0 + g0);
        const float4* P = (const float4*)(table + (size_t)u0 * 16);
        float4 a0 = P[0], a1 = P[1], a2 = P[2];

        bool hasB = (mask != 0ull);
        float4 b0, b1, b2;
        if (hasB) {
            int g1 = (int)__builtin_ctzll(mask); mask &= mask - 1;
            int u1 = __builtin_amdgcn_readfirstlane(c0 + g1);
            const float4* Q = (const float4*)(table + (size_t)u1 * 16);
            b0 = Q[0]; b1 = Q[1]; b2 = Q[2];
        }

        while (true) {
            bool hasC = (mask != 0ull);
            float4 e0, e1, e2;
            if (hasC) {
                int g2 = (int)__builtin_ctzll(mask); mask &= mask - 1;
                int u2 = __builtin_amdgcn_readfirstlane(c0 + g2);
                const float4* Q = (const float4*)(table + (size_t)u2 * 16);
                e0 = Q[0]; e1 = Q[1]; e2 = Q[2];
            }

            // all a* operands are SGPRs: <=1 SGPR per VALU instr holds throughout
            float dy = py - a2.y, dz = pz - a2.z;
            float qyz = (a0.y * dy) * dy + (a0.z * dz + a1.y * dy) * dz;
            float gx  = a0.w * dy + a1.x * dz;
            float qmin = qyz - (gx * gx) * a1.z;   // scaled max of q' = min of q
            if (!__all(qmin < SKIPTH)) {           // some lane's strip reaches q < QCUT
                float dx0 = px - a2.x;
                float dx1 = dx0 + VOXF;
                float dx2 = dx0 + 2.0f * VOXF;
                float dx3 = dx0 + 3.0f * VOXF;
                float q0 = qyz + dx0 * (a0.x * dx0 + gx);
                float q1 = qyz + dx1 * (a0.x * dx1 + gx);
                float q2 = qyz + dx2 * (a0.x * dx2 + gx);
                float q3 = qyz + dx3 * (a0.x * dx3 + gx);
                float de = a1.w;
                acc.x += de * __builtin_amdgcn_exp2f(q0);
                acc.y += de * __builtin_amdgcn_exp2f(q1);
                acc.z += de * __builtin_amdgcn_exp2f(q2);
                acc.w += de * __builtin_amdgcn_exp2f(q3);
            }

            if (!hasB) break;
            a0 = b0; a1 = b1; a2 = b2;
            hasB = hasC;
            if (hasC) { b0 = e0; b1 = e1; b2 = e2; }
        }
    }

    plds[wave][lane] = acc;
    __syncthreads();

    if (wave == 0) {
        float4 r = plds[0][lane];
        #pragma unroll
        for (int w = 1; w < 8; ++w) {       // fixed order: deterministic
            float4 p = plds[w][lane];
            r.x += p.x; r.y += p.y; r.z += p.z; r.w += p.w;
        }
        const int v = (z << 12) + (y << 6) + x;
        *(float4*)&out[v] = r;
    }
}

extern "C" void kernel_launch(void* const* d_in, const int* in_sizes, int n_in,
                              void* d_out, int out_size, void* d_ws, size_t ws_size,
                              hipStream_t stream)
{
    const float* means  = (const float*)d_in[0];
    const float* dens   = (const float*)d_in[1];
    const float* scales = (const float*)d_in[2];
    const float* rots   = (const float*)d_in[3];
    float* out = (float*)d_out;
    float* table = (float*)d_ws;   // N*64 bytes
    const int N = in_sizes[1];

    prep_kernel<<<(N + 255) / 256, 256, 0, stream>>>(means, dens, scales, rots,
                                                     table, out + NVOX, N);
    vox_kernel<<<1024, 512, 0, stream>>>(table, out, N);
}

// Round 8
// 42.077 us; speedup vs baseline: 10.3327x; 1.0013x over previous
//
#include <hip/hip_runtime.h>

#define GRIDN 64
#define NVOX (GRIDN * GRIDN * GRIDN)
#define VOXF (1.0f / 64.0f)
#define QCUT 20.0f               // exp(-10) truncation; added error ~3e-3 << 0.24 threshold
#define EXPSCL (-0.72134752044f) // -0.5 * log2(e); folded into table coefficients
#define SKIPTH (QCUT * EXPSCL)   // q' < this  <=>  q > QCUT

// Table layout per gaussian: 16 floats (64B, one cache line). Quadratic-form
// coefficients are PRE-SCALED by EXPSCL so exp2(q') is used directly.
//  f4[0] = (A', B', C', 2D')      scaled inverse covariance
//  f4[1] = (2E', 2F', 0.25/A', density)
//  f4[2] = (mux, muy, muz, 0)
//  f4[3] = (rx, ry, rz, 0)        exact ellipsoid AABB half-widths at q=QCUT

__global__ __launch_bounds__(256) void prep_kernel(
    const float* __restrict__ means, const float* __restrict__ dens,
    const float* __restrict__ scales, const float* __restrict__ rots,
    float* __restrict__ table, float* __restrict__ radii_out, int N)
{
    int i = blockIdx.x * 256 + threadIdx.x;
    if (i >= N) return;

    float qw = rots[i * 4 + 0], qx = rots[i * 4 + 1];
    float qy = rots[i * 4 + 2], qz = rots[i * 4 + 3];
    float inm = rsqrtf(qw * qw + qx * qx + qy * qy + qz * qz);
    qw *= inm; qx *= inm; qy *= inm; qz *= inm;
    float r00 = 1.f - 2.f * (qy * qy + qz * qz);
    float r01 = 2.f * (qx * qy - qw * qz);
    float r02 = 2.f * (qx * qz + qw * qy);
    float r10 = 2.f * (qx * qy + qw * qz);
    float r11 = 1.f - 2.f * (qx * qx + qz * qz);
    float r12 = 2.f * (qy * qz - qw * qx);
    float r20 = 2.f * (qx * qz - qw * qy);
    float r21 = 2.f * (qy * qz + qw * qx);
    float r22 = 1.f - 2.f * (qx * qx + qy * qy);

    float s0 = scales[i * 3 + 0], s1 = scales[i * 3 + 1], s2 = scales[i * 3 + 2];
    float v0 = s0 * s0, v1 = s1 * s1, v2 = s2 * s2;
    float i0 = 1.f / v0, i1 = 1.f / v1, i2 = 1.f / v2;

    // Sinv = R diag(1/s^2) R^T, then scale by EXPSCL
    float A = (r00 * r00 * i0 + r01 * r01 * i1 + r02 * r02 * i2) * EXPSCL;
    float B = (r10 * r10 * i0 + r11 * r11 * i1 + r12 * r12 * i2) * EXPSCL;
    float C = (r20 * r20 * i0 + r21 * r21 * i1 + r22 * r22 * i2) * EXPSCL;
    float D = (r00 * r10 * i0 + r01 * r11 * i1 + r02 * r12 * i2) * EXPSCL;
    float E = (r00 * r20 * i0 + r01 * r21 * i1 + r02 * r22 * i2) * EXPSCL;
    float F = (r10 * r20 * i0 + r11 * r21 * i1 + r12 * r22 * i2) * EXPSCL;

    // Covariance diagonal (Sigma = R diag(s^2) R^T) -> exact AABB of {q<=QCUT}
    float Cxx = r00 * r00 * v0 + r01 * r01 * v1 + r02 * r02 * v2;
    float Cyy = r10 * r10 * v0 + r11 * r11 * v1 + r12 * r12 * v2;
    float Czz = r20 * r20 * v0 + r21 * r21 * v1 + r22 * r22 * v2;

    float4* T = (float4*)(table + (size_t)i * 16);
    float4 w0; w0.x = A; w0.y = B; w0.z = C; w0.w = 2.f * D;
    float4 w1; w1.x = 2.f * E; w1.y = 2.f * F; w1.z = 0.25f / A; w1.w = dens[i];
    float4 w2; w2.x = means[i * 3 + 0]; w2.y = means[i * 3 + 1]; w2.z = means[i * 3 + 2]; w2.w = 0.f;
    float4 w3; w3.x = sqrtf(QCUT * Cxx); w3.y = sqrtf(QCUT * Cyy); w3.z = sqrtf(QCUT * Czz); w3.w = 0.f;
    T[0] = w0; T[1] = w1; T[2] = w2; T[3] = w3;

    float m = fmaxf(s0, fmaxf(s1, s2));
    radii_out[i] = ceilf(m * 3.0f * 64.0f);
}

// 4096 blocks x 256 threads (4 waves). Tile = 8x8x4 voxels (VPT=4 along x);
// each tile is covered by 4 blocks, each owning a disjoint quarter of the
// gaussian chunks (chunk c -> quarter c&3, wave (c>>2)&3). 16384 waves = 2x
// device capacity -> dynamic refill balances the heavy-tile tail. Quarter
// partials go to d_ws; a combine kernel sums them in fixed order.
__global__ __launch_bounds__(256) void vox_kernel(
    const float* __restrict__ table, float* __restrict__ part, int N)
{
    __shared__ float4 plds[4][64];

    const int tid = threadIdx.x;
    const int lane = tid & 63, wave = tid >> 6;
    // bijective scramble (gcd(1657,4096)=1): spread heavy regions across CUs
    const int bs = (blockIdx.x * 1657) & 4095;
    const int tile = bs >> 2, q = bs & 3;
    const int tX = tile & 7, tY = (tile >> 3) & 7, tZ = tile >> 6;  // 8 x 8 x 16 tiles
    const int x = (tX << 3) + ((lane & 1) << 2);   // first of this lane's 4 x-voxels
    const int y = (tY << 3) + ((lane >> 1) & 7);
    const int z = (tZ << 2) + (lane >> 4);
    const float px = (x + 0.5f) * VOXF;
    const float py = (y + 0.5f) * VOXF;
    const float pz = (z + 0.5f) * VOXF;

    const float lox = ((tX << 3) + 0.5f) * VOXF, hix = ((tX << 3) + 7.5f) * VOXF;
    const float loy = ((tY << 3) + 0.5f) * VOXF, hiy = ((tY << 3) + 7.5f) * VOXF;
    const float loz = ((tZ << 2) + 0.5f) * VOXF, hiz = ((tZ << 2) + 3.5f) * VOXF;

    float4 acc; acc.x = 0.f; acc.y = 0.f; acc.z = 0.f; acc.w = 0.f;

    const int nch = (N + 63) >> 6;
    for (int c = q + (wave << 2); c < nch; c += 16) {
        const int c0 = c << 6;
        const int gi = c0 + lane;
        const int gc = gi < N ? gi : N - 1;
        const float4* G = (const float4*)(table + (size_t)gc * 16);
        // cull needs only mu + AABB radii: 2 coalesced dwordx4 per lane
        float4 mu = G[2], rr = G[3];
        bool keep = (gi < N)
            && (mu.x + rr.x >= lox) && (mu.x - rr.x <= hix)
            && (mu.y + rr.y >= loy) && (mu.y - rr.y <= hiy)
            && (mu.z + rr.z >= loz) && (mu.z - rr.z <= hiz);

        unsigned long long mask = __ballot(keep);
        if (!mask) continue;

        // survivor loop: wave-uniform scalar loads, 2-deep prefetch
        int g0 = (int)__builtin_ctzll(mask); mask &= mask - 1;
        int u0 = __builtin_amdgcn_readfirstlane(c0 + g0);
        const float4* P = (const float4*)(table + (size_t)u0 * 16);
        float4 a0 = P[0], a1 = P[1], a2 = P[2];

        bool hasB = (mask != 0ull);
        float4 b0, b1, b2;
        if (hasB) {
            int g1 = (int)__builtin_ctzll(mask); mask &= mask - 1;
            int u1 = __builtin_amdgcn_readfirstlane(c0 + g1);
            const float4* Q = (const float4*)(table + (size_t)u1 * 16);
            b0 = Q[0]; b1 = Q[1]; b2 = Q[2];
        }

        while (true) {
            bool hasC = (mask != 0ull);
            float4 e0, e1, e2;
            if (hasC) {
                int g2 = (int)__builtin_ctzll(mask); mask &= mask - 1;
                int u2 = __builtin_amdgcn_readfirstlane(c0 + g2);
                const float4* Q = (const float4*)(table + (size_t)u2 * 16);
                e0 = Q[0]; e1 = Q[1]; e2 = Q[2];
            }

            // all a* operands are SGPRs: <=1 SGPR per VALU instr holds throughout
            float dy = py - a2.y, dz = pz - a2.z;
            float qyz = (a0.y * dy) * dy + (a0.z * dz + a1.y * dy) * dz;
            float gx  = a0.w * dy + a1.x * dz;
            float qmin = qyz - (gx * gx) * a1.z;   // scaled max of q' = min of q
            if (!__all(qmin < SKIPTH)) {           // some lane's strip reaches q < QCUT
                float dx0 = px - a2.x;
                float dx1 = dx0 + VOXF;
                float dx2 = dx0 + 2.0f * VOXF;
                float dx3 = dx0 + 3.0f * VOXF;
                float q0 = qyz + dx0 * (a0.x * dx0 + gx);
                float q1 = qyz + dx1 * (a0.x * dx1 + gx);
                float q2 = qyz + dx2 * (a0.x * dx2 + gx);
                float q3 = qyz + dx3 * (a0.x * dx3 + gx);
                float de = a1.w;
                acc.x += de * __builtin_amdgcn_exp2f(q0);
                acc.y += de * __builtin_amdgcn_exp2f(q1);
                acc.z += de * __builtin_amdgcn_exp2f(q2);
                acc.w += de * __builtin_amdgcn_exp2f(q3);
            }

            if (!hasB) break;
            a0 = b0; a1 = b1; a2 = b2;
            hasB = hasC;
            if (hasC) { b0 = e0; b1 = e1; b2 = e2; }
        }
    }

    plds[wave][lane] = acc;
    __syncthreads();

    if (wave == 0) {
        float4 r = plds[0][lane];
        #pragma unroll
        for (int w = 1; w < 4; ++w) {       // fixed order: deterministic
            float4 p = plds[w][lane];
            r.x += p.x; r.y += p.y; r.z += p.z; r.w += p.w;
        }
        const int v = (z << 12) + (y << 6) + x;
        *(float4*)&part[(size_t)q * NVOX + v] = r;
    }
}

// out4[i] = sum over the 4 quarter-partials, fixed order -> deterministic
__global__ __launch_bounds__(256) void combine_kernel(
    const float* __restrict__ part, float* __restrict__ out)
{
    const int i = blockIdx.x * 256 + threadIdx.x;   // 65536 float4s
    const float4* p = (const float4*)part;
    float4 a = p[i];
    float4 b = p[i + (NVOX / 4)];
    float4 c = p[i + 2 * (NVOX / 4)];
    float4 d = p[i + 3 * (NVOX / 4)];
    float4 r;
    r.x = ((a.x + b.x) + c.x) + d.x;
    r.y = ((a.y + b.y) + c.y) + d.y;
    r.z = ((a.z + b.z) + c.z) + d.z;
    r.w = ((a.w + b.w) + c.w) + d.w;
    ((float4*)out)[i] = r;
}

extern "C" void kernel_launch(void* const* d_in, const int* in_sizes, int n_in,
                              void* d_out, int out_size, void* d_ws, size_t ws_size,
                              hipStream_t stream)
{
    const float* means  = (const float*)d_in[0];
    const float* dens   = (const float*)d_in[1];
    const float* scales = (const float*)d_in[2];
    const float* rots   = (const float*)d_in[3];
    float* out = (float*)d_out;
    float* table = (float*)d_ws;                    // N*64 bytes
    float* part  = (float*)d_ws + (size_t)4096 * 16; // 4*NVOX floats (16 MB region)
    const int N = in_sizes[1];

    prep_kernel<<<(N + 255) / 256, 256, 0, stream>>>(means, dens, scales, rots,
                                                     table, out + NVOX, N);
    vox_kernel<<<4096, 256, 0, stream>>>(table, part, N);
    combine_kernel<<<NVOX / 4 / 256, 256, 0, stream>>>(part, out);
}